// Round 2
// 322.501 us; speedup vs baseline: 1.0484x; 1.0484x over previous
//
#include <hip/hip_runtime.h>
#include <hip/hip_bf16.h>
#include <math.h>

// Problem constants (StructureGuidedAttention: B=4, S=1024, D=1024, H=16, dk=64, G=7)
#define BB 4
#define SS 1024
#define DD 1024
#define NH 16
#define DK 64
#define GD 7

typedef _Float16 half8 __attribute__((ext_vector_type(8)));
typedef _Float16 half4v __attribute__((ext_vector_type(4)));
typedef float floatx4 __attribute__((ext_vector_type(4)));

// async global->LDS 16B DMA. Dest is wave-uniform base + lane*16 (linear);
// swizzling is done by PRE-SWIZZLING the per-lane global source address.
__device__ __forceinline__ void async_cp16(const void* g, void* l) {
  __builtin_amdgcn_global_load_lds(
      (const __attribute__((address_space(1))) void*)g,
      (__attribute__((address_space(3))) void*)l, 16, 0, 0);
}

__device__ inline half8 cvt8(const float4 a, const float4 b) {
  half8 h;
  h[0] = (_Float16)a.x; h[1] = (_Float16)a.y; h[2] = (_Float16)a.z; h[3] = (_Float16)a.w;
  h[4] = (_Float16)b.x; h[5] = (_Float16)b.y; h[6] = (_Float16)b.z; h[7] = (_Float16)b.w;
  return h;
}

// ---------------------------------------------------------------------------
// prep: blocks 0..2047 = x fp32 -> f16; blocks 2048..3071 = pack W^T f16.
// ---------------------------------------------------------------------------
__global__ __launch_bounds__(256) void prep(const float* __restrict__ x,
                                            _Float16* __restrict__ xh,
                                            const float* __restrict__ Wq,
                                            const float* __restrict__ Wk,
                                            const float* __restrict__ Wv,
                                            const float* __restrict__ Wo,
                                            _Float16* __restrict__ Wt) {
  __shared__ _Float16 Tl[64 * 72];  // packw transpose tile [n][k], pitch 72
  const int t = threadIdx.x;
  if (blockIdx.x < 2048) {  // ---- cvtx ----
    const int i = blockIdx.x * 256 + t;
    const float4 a = ((const float4*)x)[i * 2];
    const float4 b = ((const float4*)x)[i * 2 + 1];
    ((half8*)xh)[i] = cvt8(a, b);
    return;
  }
  // ---- packw: 64x64 LDS tile transpose ----
  const int pf = blockIdx.x - 2048;
  const int z = pf >> 8, rem = pf & 255;
  const int n0 = (rem >> 4) * 64, k0 = (rem & 15) * 64;
  const float* src = (z == 0) ? Wq : (z == 1) ? Wk : (z == 2) ? Wv : Wo;
#pragma unroll
  for (int i = 0; i < 4; ++i) {
    const int u = i * 256 + t;
    const int r = u >> 4, c4 = (u & 15) * 4;
    const float4 v = *(const float4*)(src + (size_t)(k0 + r) * DD + n0 + c4);
    Tl[(c4 + 0) * 72 + r] = (_Float16)v.x;
    Tl[(c4 + 1) * 72 + r] = (_Float16)v.y;
    Tl[(c4 + 2) * 72 + r] = (_Float16)v.z;
    Tl[(c4 + 3) * 72 + r] = (_Float16)v.w;
  }
  __syncthreads();
  _Float16* dst = Wt + (size_t)z * DD * DD;
#pragma unroll
  for (int i = 0; i < 2; ++i) {
    const int u = i * 256 + t;
    const int nr = u >> 3, ks = u & 7;
    const half8 hv = *(const half8*)&Tl[nr * 72 + ks * 8];
    *(half8*)(dst + (size_t)(n0 + nr) * DD + k0 + ks * 8) = hv;
  }
}

// ---------------------------------------------------------------------------
// fused0: QKV hgemm (768 virtual blocks) + biasprep->fp8 (2048 virtual blocks),
// role-INTERLEAVED 3:8 over 2816 = 11*256 blocks.
// GEMM staging uses global_load_lds (16B) with pre-swizzled global source
// (XOR seg^row&7) + linear LDS; reads apply the same XOR -> conflict-free and
// no VGPR roundtrip for staging.
// ---------------------------------------------------------------------------
template <bool PRE>
__global__ __launch_bounds__(256) void fused0(const _Float16* __restrict__ A,
                                              const _Float16* __restrict__ Bt,
                                              const float* __restrict__ bq,
                                              const float* __restrict__ bk,
                                              const float* __restrict__ bv,
                                              _Float16* __restrict__ Oq,
                                              _Float16* __restrict__ Ok,
                                              _Float16* __restrict__ Ov,
                                              const float* __restrict__ geom,
                                              const int* __restrict__ mask,
                                              const float* __restrict__ Wg,
                                              const float* __restrict__ bg,
                                              unsigned char* __restrict__ bias8) {
  const int t = threadIdx.x;
  int role, idx;
  if (PRE) {
    const int g = blockIdx.x, grp = g / 11, rem = g % 11;  // 2816 = 11*256, 768:2048 = 3:8
    if (rem < 3) { role = 0; idx = grp * 3 + rem; }
    else         { role = 1; idx = grp * 8 + rem - 3; }
  } else {
    role = 0; idx = blockIdx.x;
  }

  if (role == 0) {
    // ================= QKV GEMM =================
    __shared__ _Float16 Als[128 * 64];  // [m][k] linear, XOR-swizzled segs
    __shared__ _Float16 Bls[128 * 64];  // [n][k]
    const int w = t >> 6, lane = t & 63, quad = lane >> 4, col = lane & 15;
    const int m0 = (idx & 31) * 128, n0 = (idx >> 5) * 128;
    const int mw = (w >> 1) * 64, nw = (w & 1) * 64;
    const int lr = lane >> 3, ls = lane & 7;
    const int swz8 = (ls ^ lr) * 8;  // pre-swizzled k-seg (halfs)
    const floatx4 zero4 = {0.f, 0.f, 0.f, 0.f};
    floatx4 acc[4][4];
#pragma unroll
    for (int i = 0; i < 4; ++i)
#pragma unroll
      for (int j = 0; j < 4; ++j) acc[i][j] = zero4;

    const _Float16* aBase = A + (size_t)(m0 + lr) * DD + swz8;
    const _Float16* bBase = Bt + (size_t)(n0 + lr) * DD + swz8;

    for (int k0 = 0; k0 < DD; k0 += 64) {
#pragma unroll
      for (int it = 0; it < 4; ++it) {
        const int rb = it * 32 + w * 8;
        async_cp16(aBase + (size_t)rb * DD + k0, &Als[rb * 64]);
        async_cp16(bBase + (size_t)rb * DD + k0, &Bls[rb * 64]);
      }
      __syncthreads();
#pragma unroll
      for (int kk = 0; kk < 2; ++kk) {
        half8 af[4], bf[4];
        const int sz = ((quad + kk * 4) ^ (col & 7)) * 8;
#pragma unroll
        for (int i = 0; i < 4; ++i)
          af[i] = *(const half8*)&Als[(mw + i * 16 + col) * 64 + sz];
#pragma unroll
        for (int j = 0; j < 4; ++j)
          bf[j] = *(const half8*)&Bls[(nw + j * 16 + col) * 64 + sz];
#pragma unroll
        for (int i = 0; i < 4; ++i)
#pragma unroll
          for (int j = 0; j < 4; ++j)
            acc[i][j] =
                __builtin_amdgcn_mfma_f32_16x16x32_f16(af[i], bf[j], acc[i][j], 0, 0, 0);
      }
      __syncthreads();
    }

#pragma unroll
    for (int j = 0; j < 4; ++j) {
      const int n = n0 + nw + j * 16 + col;
      const int which = n >> 10, hd = n & 1023;
      const int h = hd >> 6, d = hd & 63;
      const float* bp = (which == 0) ? bq : (which == 1) ? bk : bv;
      const float bias = bp[hd];
      _Float16* ob = (which == 0) ? Oq : (which == 1) ? Ok : Ov;
#pragma unroll
      for (int i = 0; i < 4; ++i) {
#pragma unroll
        for (int reg = 0; reg < 4; ++reg) {
          const int m = m0 + mw + i * 16 + quad * 4 + reg;
          const int b = m >> 10, s = m & 1023;
          ob[(((size_t)b * NH + h) * SS + s) * DK + d] = (_Float16)(acc[i][j][reg] + bias);
        }
      }
    }
    return;
  }

  if constexpr (PRE) {
    // ============ biasprep: 8 keys/thread, 16 heads, fp8 output ============
    __shared__ float wgL[GD * NH + NH];
    const int r = idx;                        // 0..2047
    const int b = r >> 9;                     // 0..3
    const int q = (r & 511) * 2 + (t >> 7);   // 2 q-rows per block
    const int k8 = (t & 127) * 8;             // 8 consecutive keys
    if (t < GD * NH) wgL[t] = Wg[t];
    if (t < NH) wgL[GD * NH + t] = bg[t];

    const float* gp = geom + ((size_t)b * SS + q) * SS * GD + (size_t)k8 * GD;
    float4 gv[14];  // 8 keys x 7 features
#pragma unroll
    for (int i = 0; i < 14; ++i) gv[i] = *(const float4*)(gp + i * 4);
    const float* gf = (const float*)gv;

    const int4 m4a = *(const int4*)(mask + b * SS + k8);
    const int4 m4b = *(const int4*)(mask + b * SS + k8 + 4);
    const int mk[8] = {m4a.x, m4a.y, m4a.z, m4a.w, m4b.x, m4b.y, m4b.z, m4b.w};

    __syncthreads();

    unsigned char* dst = bias8 + ((size_t)b * NH * SS + q) * SS + k8;
#pragma unroll
    for (int h = 0; h < NH; ++h) {
      float wg[GD];
#pragma unroll
      for (int g = 0; g < GD; ++g) wg[g] = wgL[g * NH + h];  // broadcast reads
      const float bgh = wgL[GD * NH + h];
      float bi[8];
#pragma unroll
      for (int k2 = 0; k2 < 8; ++k2) {
        float s = bgh;
#pragma unroll
        for (int g = 0; g < GD; ++g) s = fmaf(gf[k2 * GD + g], wg[g], s);
        bi[k2] = mk[k2] ? s : -100.f;
      }
      // pack 8 floats -> 8 fp8 e4m3 (HW cvt_pk)
      int w0 = 0, w1 = 0;
      w0 = __builtin_amdgcn_cvt_pk_fp8_f32(bi[0], bi[1], w0, false);
      w0 = __builtin_amdgcn_cvt_pk_fp8_f32(bi[2], bi[3], w0, true);
      w1 = __builtin_amdgcn_cvt_pk_fp8_f32(bi[4], bi[5], w1, false);
      w1 = __builtin_amdgcn_cvt_pk_fp8_f32(bi[6], bi[7], w1, true);
      uint2 u2v;
      u2v.x = (unsigned)w0;
      u2v.y = (unsigned)w1;
      *(uint2*)(dst + (size_t)h * SS * SS) = u2v;
    }
  }
}

// ---------------------------------------------------------------------------
// Out-projection hgemm: C[4096][1024] = ctxh @ Wt(o)^T + bo -> fp32 d_out
// (same global_load_lds staging as fused0 GEMM role)
// ---------------------------------------------------------------------------
__global__ __launch_bounds__(256) void hgemm1(const _Float16* __restrict__ A,
                                              const _Float16* __restrict__ Bt,
                                              const float* __restrict__ b0,
                                              float* __restrict__ Of) {
  __shared__ _Float16 Als[128 * 64];
  __shared__ _Float16 Bls[128 * 64];
  const int t = threadIdx.x;
  const int w = t >> 6, lane = t & 63, quad = lane >> 4, col = lane & 15;
  const int m0 = blockIdx.x * 128, n0 = blockIdx.y * 128;
  const int mw = (w >> 1) * 64, nw = (w & 1) * 64;
  const int lr = lane >> 3, ls = lane & 7;
  const int swz8 = (ls ^ lr) * 8;
  const floatx4 zero4 = {0.f, 0.f, 0.f, 0.f};
  floatx4 acc[4][4];
#pragma unroll
  for (int i = 0; i < 4; ++i)
#pragma unroll
    for (int j = 0; j < 4; ++j) acc[i][j] = zero4;

  const _Float16* aBase = A + (size_t)(m0 + lr) * DD + swz8;
  const _Float16* bBase = Bt + (size_t)(n0 + lr) * DD + swz8;

  for (int k0 = 0; k0 < DD; k0 += 64) {
#pragma unroll
    for (int it = 0; it < 4; ++it) {
      const int rb = it * 32 + w * 8;
      async_cp16(aBase + (size_t)rb * DD + k0, &Als[rb * 64]);
      async_cp16(bBase + (size_t)rb * DD + k0, &Bls[rb * 64]);
    }
    __syncthreads();
#pragma unroll
    for (int kk = 0; kk < 2; ++kk) {
      half8 af[4], bf[4];
      const int sz = ((quad + kk * 4) ^ (col & 7)) * 8;
#pragma unroll
      for (int i = 0; i < 4; ++i) af[i] = *(const half8*)&Als[(mw + i * 16 + col) * 64 + sz];
#pragma unroll
      for (int j = 0; j < 4; ++j) bf[j] = *(const half8*)&Bls[(nw + j * 16 + col) * 64 + sz];
#pragma unroll
      for (int i = 0; i < 4; ++i)
#pragma unroll
        for (int j = 0; j < 4; ++j)
          acc[i][j] = __builtin_amdgcn_mfma_f32_16x16x32_f16(af[i], bf[j], acc[i][j], 0, 0, 0);
    }
    __syncthreads();
  }

#pragma unroll
  for (int j = 0; j < 4; ++j) {
    const int n = n0 + nw + j * 16 + col;
    const float bias = b0[n];
#pragma unroll
    for (int i = 0; i < 4; ++i) {
#pragma unroll
      for (int reg = 0; reg < 4; ++reg) {
        const int m = m0 + mw + i * 16 + quad * 4 + reg;
        Of[(size_t)m * DD + n] = acc[i][j][reg] + bias;
      }
    }
  }
}

// ---------------------------------------------------------------------------
// MFMA flash attention, f16 Q/K/V, f16 ctx out — SWAPPED-OPERAND layout.
// QK^T computed as mfma(K,Q) so S[key = nt*16+quad*4+reg][q = col]:
//   * bias read becomes one u32 per nt (4 consecutive fp8 bytes, literal sel)
//   * P -> PV hand-off is LANE-LOCAL: V^T columns are stored bit-permuted
//     (c = {kk,Q1,Q0,e2,e1,e0} holds key {kk,e2,Q1,Q0,e1,e0}) so the PV
//     B-operand half8 is just the thread's own 8 exp() values. No P LDS.
//   * ctx epilogue: 4 consecutive d per thread -> half4 stores; 2-shuffle lsum.
// K/Q staged via global_load_lds with pre-swizzled source (seg ^ row&7).
// ---------------------------------------------------------------------------
template <bool PREBIAS>
__global__ __launch_bounds__(256) void attn(const _Float16* __restrict__ Q,
                                            const _Float16* __restrict__ K,
                                            const _Float16* __restrict__ V,
                                            const unsigned char* __restrict__ bias8,
                                            const float* __restrict__ geom,
                                            const int* __restrict__ mask,
                                            const float* __restrict__ Wg,
                                            const float* __restrict__ bg,
                                            _Float16* __restrict__ ctxbuf) {
  __shared__ _Float16 Ks[64 * 64];      // K chunk, half8 XOR-swizzled (Q staging pre-loop)
  __shared__ _Float16 Vt[64 * 72];      // V^T chunk [dim][perm-key], pitch 72
  __shared__ unsigned char biasL[PREBIAS ? 64 * 80 : 64 * 144];  // fp8 pitch-80B | f16 pitch-72el
  __shared__ unsigned char mskL[SS];    // fallback only

  const int t = threadIdx.x;
  const int w = t >> 6, lane = t & 63, quad = lane >> 4, col = lane & 15;
  const int h = blockIdx.x, qt = blockIdx.y, b = blockIdx.z;
  const int q0 = qt * 64;
  const size_t bh = (size_t)b * NH + h;
  const _Float16* Qb = Q + bh * SS * DK;
  const _Float16* Kb = K + bh * SS * DK;
  const _Float16* Vb = V + bh * SS * DK;
  _Float16* biasLf = (_Float16*)biasL;

  const int lr = lane >> 3, ls = lane & 7;
  const int swz8 = (ls ^ lr) * 8;

  {  // stage Q tile into Ks via async DMA, pre-swizzled source
#pragma unroll
    for (int it = 0; it < 2; ++it) {
      const int rb = it * 32 + w * 8;
      async_cp16(Qb + (size_t)(q0 + rb + lr) * DK + swz8, &Ks[rb * 64]);
    }
  }
  if constexpr (!PREBIAS) {
    const int4 m4 = *(const int4*)(mask + b * SS + t * 4);
    mskL[t * 4 + 0] = m4.x != 0;
    mskL[t * 4 + 1] = m4.y != 0;
    mskL[t * 4 + 2] = m4.z != 0;
    mskL[t * 4 + 3] = m4.w != 0;
  }
  __syncthreads();
  half8 qfrag[2];
  {
    const int qrow = w * 16 + col;
#pragma unroll
    for (int kk = 0; kk < 2; ++kk)
      qfrag[kk] = *(const half8*)&Ks[qrow * 64 + (((quad + kk * 4) ^ (col & 7)) * 8)];
  }

  float wgv[GD];
  float bgh = 0.f;
  const float* gptr = nullptr;
  if constexpr (!PREBIAS) {
#pragma unroll
    for (int g = 0; g < GD; ++g) wgv[g] = Wg[g * NH + h];
    bgh = bg[h];
    gptr = geom + (((size_t)b * SS + (q0 + (t >> 2))) * SS + (t & 3) * 16) * GD;
  }
  const unsigned char* bb8 = nullptr;
  if constexpr (PREBIAS) bb8 = bias8 + (bh * SS + q0) * SS;

  const floatx4 zero4 = {0.f, 0.f, 0.f, 0.f};
  floatx4 ctx[4] = {zero4, zero4, zero4, zero4};
  float lsum = 0.f;

  // V^T column permutation: key a -> column c(a)
  // c = (a & 0b100011) | ((a & 0b001100) << 1) | ((a & 0b010000) >> 2)
  const int kg = (t >> 4) * 4, dg = (t & 15) * 4;
  const int cg = (kg & 0x20) | ((kg & 0x0C) << 1) | ((kg & 0x10) >> 2);

  for (int c = 0; c < 16; ++c) {
    const int k0c = c * 64;
    __syncthreads();

    {  // K chunk via async DMA, pre-swizzled source
#pragma unroll
      for (int it = 0; it < 2; ++it) {
        const int rb = it * 32 + w * 8;
        async_cp16(Kb + (size_t)(k0c + rb + lr) * DK + swz8, &Ks[rb * 64]);
      }
    }
    {  // V^T chunk via 4x4 register transpose into PERMUTED columns
      half4v f[4];
#pragma unroll
      for (int e = 0; e < 4; ++e)
        f[e] = *(const half4v*)(Vb + (size_t)(k0c + kg + e) * DK + dg);
#pragma unroll
      for (int i = 0; i < 4; ++i) {
        half4v hv = {f[0][i], f[1][i], f[2][i], f[3][i]};
        *(half4v*)&Vt[(dg + i) * 72 + cg] = hv;
      }
    }
    if constexpr (PREBIAS) {  // fp8 bias chunk: one uint4 (16 keys) per thread
      const int row = t >> 2, seg = (t & 3) * 16;
      const uint4 v = *(const uint4*)(bb8 + (size_t)row * SS + k0c + seg);
      *(uint4*)&biasL[row * 80 + seg] = v;
    } else {  // inline geom bias (fallback)
      const int gq = t >> 2, gk = (t & 3) * 16;
#pragma unroll
      for (int sg = 0; sg < 4; ++sg) {
        float4 gvv[7];
#pragma unroll
        for (int i7 = 0; i7 < 7; ++i7) gvv[i7] = *(const float4*)(gptr + sg * 28 + i7 * 4);
        const float* gf = (const float*)gvv;
        half4v bv;
#pragma unroll
        for (int k2 = 0; k2 < 4; ++k2) {
          float bi = bgh;
#pragma unroll
          for (int g = 0; g < GD; ++g) bi = fmaf(gf[k2 * GD + g], wgv[g], bi);
          bv[k2] = mskL[k0c + gk + sg * 4 + k2] ? (_Float16)bi : (_Float16)(-100.f);
        }
        *(half4v*)&biasLf[gq * 72 + gk + sg * 4] = bv;
      }
      gptr += 64 * GD;
    }
    __syncthreads();

    // ---- QK^T SWAPPED: sc[nt][reg] = S[key = nt*16+quad*4+reg][q = col] ----
    floatx4 sc[4] = {zero4, zero4, zero4, zero4};
#pragma unroll
    for (int nt = 0; nt < 4; ++nt) {
      const int key = nt * 16 + col;
#pragma unroll
      for (int kk = 0; kk < 2; ++kk) {
        const half8 kf = *(const half8*)&Ks[key * 64 + (((quad + kk * 4) ^ (col & 7)) * 8)];
        sc[nt] = __builtin_amdgcn_mfma_f32_16x16x32_f16(kf, qfrag[kk], sc[nt], 0, 0, 0);
      }
    }

    // ---- p = exp(s/8 + bias); bias: one u32 per nt, literal-sel converts ----
    float ps[4][4];
#pragma unroll
    for (int nt = 0; nt < 4; ++nt) {
      float bias4[4];
      if constexpr (PREBIAS) {
        const unsigned bw =
            *(const unsigned*)&biasL[(w * 16 + col) * 80 + nt * 16 + quad * 4];
        bias4[0] = __builtin_amdgcn_cvt_f32_fp8((int)bw, 0);
        bias4[1] = __builtin_amdgcn_cvt_f32_fp8((int)bw, 1);
        bias4[2] = __builtin_amdgcn_cvt_f32_fp8((int)bw, 2);
        bias4[3] = __builtin_amdgcn_cvt_f32_fp8((int)bw, 3);
      } else {
#pragma unroll
        for (int reg = 0; reg < 4; ++reg)
          bias4[reg] = (float)biasLf[(w * 16 + col) * 72 + nt * 16 + quad * 4 + reg];
      }
#pragma unroll
      for (int reg = 0; reg < 4; ++reg) {
        const float s = fmaf(sc[nt][reg], 0.125f, bias4[reg]);
        const float p = __expf(s);
        lsum += p;
        ps[nt][reg] = p;
      }
    }

    // ---- PV: B-operand is LANE-LOCAL (keys match permuted V^T columns) ----
#pragma unroll
    for (int kk = 0; kk < 2; ++kk) {
      half8 pf;
      pf[0] = (_Float16)ps[2 * kk][0];
      pf[1] = (_Float16)ps[2 * kk][1];
      pf[2] = (_Float16)ps[2 * kk][2];
      pf[3] = (_Float16)ps[2 * kk][3];
      pf[4] = (_Float16)ps[2 * kk + 1][0];
      pf[5] = (_Float16)ps[2 * kk + 1][1];
      pf[6] = (_Float16)ps[2 * kk + 1][2];
      pf[7] = (_Float16)ps[2 * kk + 1][3];
#pragma unroll
      for (int nt = 0; nt < 4; ++nt) {
        const half8 vb = *(const half8*)&Vt[(nt * 16 + col) * 72 + quad * 8 + kk * 32];
        ctx[nt] = __builtin_amdgcn_mfma_f32_16x16x32_f16(vb, pf, ctx[nt], 0, 0, 0);
      }
    }
  }

  // lsum: per-thread covers keys {quad*4+reg mod 16}; reduce across quads.
  float l = lsum;
  l += __shfl_xor(l, 16, 64);
  l += __shfl_xor(l, 32, 64);
  const float inv = 1.f / l;

  // ctx[nt][reg] = ctx^T[d = nt*16+quad*4+reg][q = col] -> half4 stores
  _Float16* op = ctxbuf + ((size_t)b * SS + q0 + w * 16 + col) * DD + h * DK + quad * 4;
#pragma unroll
  for (int nt = 0; nt < 4; ++nt) {
    half4v o;
#pragma unroll
    for (int reg = 0; reg < 4; ++reg) o[reg] = (_Float16)(ctx[nt][reg] * inv);
    *(half4v*)(op + nt * 16) = o;
  }
}

// ---------------------------------------------------------------------------
extern "C" void kernel_launch(void* const* d_in, const int* in_sizes, int n_in,
                              void* d_out, int out_size, void* d_ws, size_t ws_size,
                              hipStream_t stream) {
  const float* x    = (const float*)d_in[0];
  const float* geom = (const float*)d_in[1];
  const int*   mask = (const int*)d_in[2];
  const float* Wq   = (const float*)d_in[3];
  const float* bq   = (const float*)d_in[4];
  const float* Wk   = (const float*)d_in[5];
  const float* bk   = (const float*)d_in[6];
  const float* Wv   = (const float*)d_in[7];
  const float* bv   = (const float*)d_in[8];
  const float* Wo   = (const float*)d_in[9];
  const float* bo   = (const float*)d_in[10];
  const float* Wg   = (const float*)d_in[11];
  const float* bg   = (const float*)d_in[12];
  float* out = (float*)d_out;

  const size_t NEL = (size_t)BB * SS * DD;  // 4,194,304
  char* p = (char*)d_ws;
  _Float16* xh   = (_Float16*)p;            p += NEL * 2;
  _Float16* Wt   = (_Float16*)p;            p += NEL * 2;
  _Float16* Qh   = (_Float16*)p;            p += NEL * 2;
  _Float16* Kh   = (_Float16*)p;            p += NEL * 2;
  _Float16* Vh   = (_Float16*)p;            p += NEL * 2;
  _Float16* ctxh = (_Float16*)p;            p += NEL * 2;       // 48 MiB base
  unsigned char* bias8 = (unsigned char*)p;                     // +64 MiB (fp8)
  const size_t need = (size_t)48 * 1024 * 1024 + (size_t)BB * NH * SS * SS;
  const bool prebias = ws_size >= need;

  prep<<<3072, 256, 0, stream>>>(x, xh, Wq, Wk, Wv, Wo, Wt);

  if (prebias) {
    fused0<true><<<2816, 256, 0, stream>>>(xh, Wt, bq, bk, bv, Qh, Kh, Vh,
                                           geom, mask, Wg, bg, bias8);
    attn<true><<<dim3(NH, SS / 64, BB), 256, 0, stream>>>(Qh, Kh, Vh, bias8, geom, mask,
                                                          Wg, bg, ctxh);
  } else {
    fused0<false><<<768, 256, 0, stream>>>(xh, Wt, bq, bk, bv, Qh, Kh, Vh,
                                           geom, mask, Wg, bg, nullptr);
    attn<false><<<dim3(NH, SS / 64, BB), 256, 0, stream>>>(Qh, Kh, Vh, nullptr, geom, mask,
                                                           Wg, bg, ctxh);
  }

  hgemm1<<<dim3(32, 8), 256, 0, stream>>>(ctxh, Wt + (size_t)3 * DD * DD, bo, out);
}